// Round 1
// baseline (905.244 us; speedup 1.0000x reference)
//
#include <hip/hip_runtime.h>
#include <hip/hip_bf16.h>

#define H 1024
#define B_TOK 16384
#define RTILES 268            // covers worst padded slot total 34048 (266 tiles) + margin
#define RCAP   (RTILES * 128) // asg / routed-hm row capacity (34304)

typedef __attribute__((ext_vector_type(8))) short s16x8;
typedef __attribute__((ext_vector_type(4))) float f32x4;

__device__ __forceinline__ short f2bf(float f) {
  __hip_bfloat16 h = __float2bfloat16(f);
  return __builtin_bit_cast(short, h);
}
__device__ __forceinline__ float bf2f(short s) {
  __hip_bfloat16 h = __builtin_bit_cast(__hip_bfloat16, s);
  return __bfloat162float(h);
}

__device__ __forceinline__ void load_lds16(const short* g, short* l) {
  __builtin_amdgcn_global_load_lds((const __attribute__((address_space(1))) void*)g,
                                   (__attribute__((address_space(3))) void*)l,
                                   16, 0, 0);
}

// ---------------- convert x -> bf16 ----------------
__global__ void cvt_x_k(const float* __restrict__ x, short* __restrict__ xb) {
  const size_t i = ((size_t)blockIdx.x * blockDim.x + threadIdx.x) * 8;
  const float4 a = *(const float4*)(x + i);
  const float4 b = *(const float4*)(x + i + 4);
  s16x8 v;
  v[0] = f2bf(a.x); v[1] = f2bf(a.y); v[2] = f2bf(a.z); v[3] = f2bf(a.w);
  v[4] = f2bf(b.x); v[5] = f2bf(b.y); v[6] = f2bf(b.z); v[7] = f2bf(b.w);
  *(s16x8*)(xb + i) = v;
}

// ---------------- transpose+convert weights ----------------
// z 0..7: w1 (shared e0,e1 then routed) -> w1t [8][1024][1024]
// z 8..9: shared w2 -> w2t_sh [1024][2048] (K-merged, col offset e*1024)
// z 10..15: routed w2 -> w2t_r [6][1024][1024]
__global__ void transpose_k(const float* __restrict__ sw1, const float* __restrict__ rw1,
                            const float* __restrict__ sw2, const float* __restrict__ rw2,
                            short* __restrict__ w1t, short* __restrict__ w2t_sh,
                            short* __restrict__ w2t_r) {
  __shared__ float tile[64][65];
  const int z = blockIdx.z;
  const float* src;
  short* dst;
  int ldd = H, koff = 0;
  if (z < 8) {
    src = (z < 2) ? sw1 + (size_t)z * H * H : rw1 + (size_t)(z - 2) * H * H;
    dst = w1t + (size_t)z * H * H;
  } else if (z < 10) {
    const int e = z - 8;
    src = sw2 + (size_t)e * H * H;
    dst = w2t_sh; ldd = 2048; koff = e * 1024;
  } else {
    const int e = z - 10;
    src = rw2 + (size_t)e * H * H;
    dst = w2t_r + (size_t)e * H * H;
  }
  const int k0 = blockIdx.y * 64, n0 = blockIdx.x * 64;
  const int t = threadIdx.x;
#pragma unroll
  for (int i = 0; i < 4; ++i) {
    const int kk = (t >> 4) + 16 * i;
    const int nn = (t & 15) * 4;
    const float4 v = *(const float4*)(src + (size_t)(k0 + kk) * H + n0 + nn);
    tile[nn + 0][kk] = v.x; tile[nn + 1][kk] = v.y;
    tile[nn + 2][kk] = v.z; tile[nn + 3][kk] = v.w;
  }
  __syncthreads();
  const int nn = t >> 2;
  const int kk = (t & 3) * 16;
  s16x8 o0, o1;
#pragma unroll
  for (int u = 0; u < 8; ++u) {
    o0[u] = f2bf(tile[nn][kk + u]);
    o1[u] = f2bf(tile[nn][kk + 8 + u]);
  }
  short* drow = dst + (size_t)(n0 + nn) * ldd + koff + k0 + kk;
  *(s16x8*)(drow) = o0;
  *(s16x8*)(drow + 8) = o1;
}

// ---------------- router phase 1: logits -> softmax -> top-2 ----------------
__global__ void logits_k(const float* __restrict__ x, const float* __restrict__ rw,
                         const float* __restrict__ rb, int2* __restrict__ tk) {
  const int lane = threadIdx.x & 63;
  const int b = blockIdx.x * 4 + (threadIdx.x >> 6);
  const float* xr = x + (size_t)b * H;
  float p[6] = {0.f, 0.f, 0.f, 0.f, 0.f, 0.f};
  for (int k = lane; k < H; k += 64) {
    const float xv = xr[k];
    const float* r = rw + k * 6;
#pragma unroll
    for (int e = 0; e < 6; ++e) p[e] += xv * r[e];
  }
#pragma unroll
  for (int e = 0; e < 6; ++e) {
    float v = p[e];
    for (int off = 32; off > 0; off >>= 1) v += __shfl_down(v, off);
    p[e] = v;
  }
  if (lane == 0) {
    float lg[6];
    float mx = -1e30f;
#pragma unroll
    for (int e = 0; e < 6; ++e) { lg[e] = p[e] + rb[e]; mx = fmaxf(mx, lg[e]); }
    float s = 0.f;
#pragma unroll
    for (int e = 0; e < 6; ++e) { lg[e] = __expf(lg[e] - mx); s += lg[e]; }
    const float inv = 1.f / s;
#pragma unroll
    for (int e = 0; e < 6; ++e) lg[e] *= inv;
    int i1 = 0;
#pragma unroll
    for (int e = 1; e < 6; ++e) if (lg[e] > lg[i1]) i1 = e;
    int i2 = (i1 == 0) ? 1 : 0;
#pragma unroll
    for (int e = 0; e < 6; ++e) if (e != i1 && lg[e] > lg[i2]) i2 = e;
    int2 v;
    v.x = i1 | ((int)(unsigned short)f2bf(lg[i1]) << 16);
    v.y = i2 | ((int)(unsigned short)f2bf(lg[i2]) << 16);
    tk[b] = v;
  }
}

// g layout (12 (rank,expert) regions, rank-major: r = rank*6 + e):
//   g[0..11]  = per-region counts (hist)
//   g[14]     = padded total, g[15] = padded end of rank-0 regions
//   g[32..43] = region starts (128-padded)
//   g[48..59] = fill counters
__global__ void hist_k(const int2* __restrict__ tk, int* __restrict__ g) {
  __shared__ int h[12];
  const int t = threadIdx.x;
  if (t < 12) h[t] = 0;
  __syncthreads();
  const int2 v = tk[blockIdx.x * 256 + t];
  atomicAdd(&h[v.x & 0xffff], 1);        // rank-0 assignment -> region e1
  atomicAdd(&h[6 + (v.y & 0xffff)], 1);  // rank-1 assignment -> region 6+e2
  __syncthreads();
  if (t < 12) atomicAdd(&g[t], h[t]);
}

__global__ void prefix_k(int* __restrict__ g) {
  if (threadIdx.x == 0) {
    int run = 0;
#pragma unroll
    for (int r = 0; r < 12; ++r) {
      g[32 + r] = run; g[48 + r] = run;
      run += (g[r] + 127) & ~127;
      if (r == 5) g[15] = run;  // rank-0 padded end
    }
    g[14] = run;  // <= 34048 worst case
  }
}

// scatter into compacted slot space; asg pre-memset to 0xFF (sentinel -1)
__global__ void scatter_k(const int2* __restrict__ tk, int* __restrict__ g,
                          int* __restrict__ asg) {
  __shared__ int lcnt[12];
  __shared__ int lbase[12];
  const int t = threadIdx.x;
  if (t < 12) lcnt[t] = 0;
  __syncthreads();
  const int tok = blockIdx.x * 256 + t;
  const int2 v = tk[tok];
  const int r1 = v.x & 0xffff;        // rank-0 region = e1
  const int r2 = 6 + (v.y & 0xffff);  // rank-1 region = 6+e2
  const int p1 = atomicAdd(&lcnt[r1], 1);
  const int p2 = atomicAdd(&lcnt[r2], 1);
  __syncthreads();
  if (t < 12) lbase[t] = atomicAdd(&g[48 + t], lcnt[t]);
  __syncthreads();
  asg[lbase[r1] + p1] = tok | (v.x & 0xffff0000);
  asg[lbase[r2] + p2] = tok | (v.y & 0xffff0000);
}

// ---------------- GEMM core, BK=64: C[128x128] = A x Bt^T ----------------
// smem: 32 chunks x 512 shorts; chunk (2*c2+kh) holds row-tile c2, k-half kh in
// exact MFMA fragment order (lane l: row c2*16+(l&15), k=kh*32+(l>>4)*8+j).
__device__ __forceinline__ void gemm_core64(const short* __restrict__ A, int lda,
                                            const short* __restrict__ Bt, int ldb, int K,
                                            short* smem, int m0, int n0,
                                            const int* __restrict__ asg, int acap,
                                            f32x4 acc[4][4]) {
  const int tid = threadIdx.x, lane = tid & 63, w = tid >> 6;
  const int q8 = (lane >> 4) * 8, r16 = lane & 15;
  const int wr = w >> 1, wc = w & 1;

  const short* gp[4];
#pragma unroll
  for (int ii = 0; ii < 4; ++ii) {
    const int c2 = w * 4 + ii;      // row-tile index 0..15 (0..7 A, 8..15 B)
    if (c2 < 8) {
      int slot = m0 + c2 * 16 + r16;
      int gr;
      if (asg) {
        int tv = asg[slot] & 0xffff;
        gr = tv < B_TOK ? tv : B_TOK - 1;   // sentinel/pad -> clamp to any valid row
      } else {
        gr = slot < acap ? slot : acap - 1;
      }
      gp[ii] = A + (size_t)gr * lda + q8;
    } else {
      gp[ii] = Bt + (size_t)(n0 + (c2 - 8) * 16 + r16) * ldb + q8;
    }
  }
  short* lbase = smem + w * 4096;

  for (int k0 = 0; k0 < K; k0 += 64) {
    __syncthreads();
#pragma unroll
    for (int i = 0; i < 8; ++i)
      load_lds16(gp[i >> 1] + k0 + (i & 1) * 32, lbase + i * 512);
    __syncthreads();
#pragma unroll
    for (int s = 0; s < 2; ++s) {
      s16x8 af[4], bfv[4];
#pragma unroll
      for (int i = 0; i < 4; ++i)
        af[i] = *(const s16x8*)(smem + ((wr * 4 + i) * 2 + s) * 512 + lane * 8);
#pragma unroll
      for (int j = 0; j < 4; ++j)
        bfv[j] = *(const s16x8*)(smem + (16 + (wc * 4 + j) * 2 + s) * 512 + lane * 8);
#pragma unroll
      for (int i = 0; i < 4; ++i)
#pragma unroll
        for (int j = 0; j < 4; ++j)
          acc[i][j] = __builtin_amdgcn_mfma_f32_16x16x32_bf16(af[i], bfv[j], acc[i][j], 0, 0, 0);
    }
  }
}

// GEMM1: Out = tanh(A @ W1 + b1) bf16, LDS-staged coalesced store.
// ROUTED=1: batched routed experts (expert from region starts, A-gather via asg)
template <int ROUTED>
__global__ __launch_bounds__(256) void gemm1_k(const short* __restrict__ A, int lda,
                                               const short* __restrict__ W1, int ldb, int K,
                                               const float* __restrict__ b1,
                                               short* __restrict__ Out, int ldo,
                                               const int* __restrict__ asg,
                                               const int* __restrict__ g, int rowcap) {
  const int m0 = blockIdx.x * 128, n0 = blockIdx.y * 128;
  const short* Bt = W1;
  const float* bias = b1;
  if (ROUTED) {
    if (m0 >= g[14]) return;
    int r = 0;
#pragma unroll
    for (int j = 1; j < 12; ++j) if (m0 >= g[32 + j]) r = j;
    const int e = r % 6;
    Bt = W1 + (size_t)e * H * H;
    bias = b1 + (size_t)e * H;
  }
  __shared__ __align__(16) short smem[16384];
  f32x4 acc[4][4];
#pragma unroll
  for (int i = 0; i < 4; ++i)
#pragma unroll
    for (int j = 0; j < 4; ++j) acc[i][j] = (f32x4){0.f, 0.f, 0.f, 0.f};
  gemm_core64(A, lda, Bt, ldb, K, smem, m0, n0, ROUTED ? asg : nullptr, 1 << 30, acc);

  const int tid = threadIdx.x, lane = tid & 63, w = tid >> 6;
  const int wr = w >> 1, wc = w & 1, q = lane >> 4, c16 = lane & 15;
  __syncthreads();
#pragma unroll
  for (int j = 0; j < 4; ++j) {
    const int colL = wc * 64 + j * 16 + c16;
    const float bv = bias[n0 + colL];
#pragma unroll
    for (int i = 0; i < 4; ++i)
#pragma unroll
      for (int r = 0; r < 4; ++r)
        smem[(wr * 64 + i * 16 + q * 4 + r) * 128 + colL] = f2bf(tanhf(acc[i][j][r] + bv));
  }
  __syncthreads();
#pragma unroll
  for (int p = 0; p < 8; ++p) {
    const int rowL = p * 16 + (tid >> 4);
    const int colL = (tid & 15) * 8;
    const int gr = m0 + rowL;
    if (gr < rowcap)
      *(s16x8*)(Out + (size_t)gr * ldo + n0 + colL) = *(const s16x8*)(smem + rowL * 128 + colL);
  }
}

// GEMM2: MODE 0 = merged shared store (LDS-staged fp32)
//        MODE 3 = routed rank-sliced scatter, plain read-modify-write (no atomics).
//                 rank slice [lo,hi): rank0 = [0, g[15]), rank1 = [g[15], g[14]).
//                 Within one rank every token appears at most once -> no write race;
//                 the two rank dispatches are stream-serialized.
template <int MODE>
__global__ __launch_bounds__(256) void gemm2_k(const short* __restrict__ A, int lda,
                                               const short* __restrict__ W2, int ldb, int K,
                                               const float* __restrict__ b2a,
                                               const float* __restrict__ b2b,
                                               float* __restrict__ Out,
                                               const int* __restrict__ asg,
                                               const int* __restrict__ g, int acap,
                                               int rank) {
  const int m0 = blockIdx.x * 128, n0 = blockIdx.y * 128;
  const short* Bt = W2;
  const float* bias = b2a;
  if (MODE == 3) {
    const int lo = rank ? g[15] : 0;
    const int hi = rank ? g[14] : g[15];
    if (m0 < lo || m0 >= hi) return;
    int r = 0;
#pragma unroll
    for (int j = 1; j < 12; ++j) if (m0 >= g[32 + j]) r = j;
    const int e = r % 6;
    Bt = W2 + (size_t)e * H * H;
    bias = b2a + (size_t)e * H;
  }
  __shared__ __align__(16) short smem[16384];
  f32x4 acc[4][4];
#pragma unroll
  for (int i = 0; i < 4; ++i)
#pragma unroll
    for (int j = 0; j < 4; ++j) acc[i][j] = (f32x4){0.f, 0.f, 0.f, 0.f};
  gemm_core64(A, lda, Bt, ldb, K, smem, m0, n0, nullptr, acap, acc);

  const int tid = threadIdx.x, lane = tid & 63, w = tid >> 6;
  const int wr = w >> 1, wc = w & 1, q = lane >> 4, c16 = lane & 15;

  if (MODE == 0) {
    float* cs = (float*)smem;  // [64][128]
    __syncthreads();
#pragma unroll
    for (int half = 0; half < 2; ++half) {
      if (wr == half) {
#pragma unroll
        for (int j = 0; j < 4; ++j) {
          const int colL = wc * 64 + j * 16 + c16;
          const float bv = b2a[n0 + colL] + b2b[n0 + colL];
#pragma unroll
          for (int i = 0; i < 4; ++i)
#pragma unroll
            for (int r = 0; r < 4; ++r)
              cs[(i * 16 + q * 4 + r) * 128 + colL] = acc[i][j][r] + bv;
        }
      }
      __syncthreads();
#pragma unroll
      for (int p = 0; p < 8; ++p) {
        const int rowL = p * 8 + (tid >> 5);
        const int colL = (tid & 31) * 4;
        *(float4*)(Out + (size_t)(m0 + half * 64 + rowL) * H + n0 + colL) =
            *(const float4*)(cs + rowL * 128 + colL);
      }
      __syncthreads();
    }
  } else {
    const int mb = m0 + wr * 64, nb = n0 + wc * 64;
#pragma unroll
    for (int i = 0; i < 4; ++i) {
      int av[4];
#pragma unroll
      for (int r = 0; r < 4; ++r) av[r] = asg[mb + i * 16 + q * 4 + r];
#pragma unroll
      for (int j = 0; j < 4; ++j) {
        const int col = nb + j * 16 + c16;
        const float bv = bias[col];
#pragma unroll
        for (int r = 0; r < 4; ++r) {
          if (av[r] == -1) continue;   // pad slot
          const int tok = av[r] & 0xffff;
          const float wt = bf2f((short)((unsigned)av[r] >> 16));
          float* p = &Out[(size_t)tok * H + col];
          *p += (acc[i][j][r] + bv) * wt;   // plain RMW -- race-free within a rank
        }
      }
    }
  }
}

extern "C" void kernel_launch(void* const* d_in, const int* in_sizes, int n_in,
                              void* d_out, int out_size, void* d_ws, size_t ws_size,
                              hipStream_t stream) {
  const float* x        = (const float*)d_in[0];
  const float* sw1      = (const float*)d_in[1];
  const float* sb1      = (const float*)d_in[2];  // [2][1024] flat
  const float* sw2      = (const float*)d_in[3];
  const float* sb2      = (const float*)d_in[4];
  const float* rw1      = (const float*)d_in[5];
  const float* rb1      = (const float*)d_in[6];
  const float* rw2      = (const float*)d_in[7];
  const float* rb2      = (const float*)d_in[8];
  const float* router_w = (const float*)d_in[9];
  const float* router_b = (const float*)d_in[10];
  float* out = (float*)d_out;

  // ws layout (high-water ~128.13 MiB, within proven >=128.38 MiB):
  //   xb      [0,          32 MiB)
  //   w1t     [32 MiB,     48 MiB)   [8][1024][1024]
  //   w2t_r   [48 MiB,     60 MiB)   [6][1024][1024]
  //   w2t_sh  [60 MiB,     64 MiB)   [1024][2048]   (dead after shared gemm2)
  //   hm_sh   [64 MiB,    128 MiB)   [16384][2048] bf16 (shared mids; tk overlay)
  //   hm_r    [60 MiB,   ~127 MiB)   [RCAP][1024] bf16 -- overlaps w2t_sh+hm_sh,
  //           both dead once routed gemm1 launches (stream-ordered); cap 34816 rows
  //   g       [128 MiB,   +256 B)
  //   asg     [.., +134 KiB)
  char* ws = (char*)d_ws;
  short* xb     = (short*)(ws);
  short* w1t    = (short*)(ws + (size_t)33554432);
  short* w2t_r  = (short*)(ws + (size_t)50331648);
  short* w2t_sh = (short*)(ws + (size_t)62914560);
  short* hm_sh  = (short*)(ws + (size_t)67108864);
  short* hm_r   = (short*)(ws + (size_t)62914560);  // capacity 34816 rows >= 34048 worst
  int2*  tk     = (int2*)hm_sh;                     // consumed before gemms write hm
  int*   g      = (int*)(ws + (size_t)134217728);
  int*   asg    = (int*)(ws + (size_t)134217984);   // RCAP*4

  hipMemsetAsync(g, 0, 64, stream);
  hipMemsetAsync(asg, 0xFF, RCAP * sizeof(int), stream);

  cvt_x_k<<<8192, 256, 0, stream>>>(x, xb);
  transpose_k<<<dim3(16, 16, 16), 256, 0, stream>>>(sw1, rw1, sw2, rw2, w1t, w2t_sh, w2t_r);
  logits_k<<<4096, 256, 0, stream>>>(x, router_w, router_b, tk);
  hist_k<<<64, 256, 0, stream>>>(tk, g);
  prefix_k<<<1, 64, 0, stream>>>(g);
  scatter_k<<<64, 256, 0, stream>>>(tk, g, asg);

  // shared experts, K-merged: GEMM1 N=2048 -> hm_sh[16384][2048]; GEMM2 K=2048 -> out
  gemm1_k<0><<<dim3(128, 16), 256, 0, stream>>>(xb, H, w1t, H, H, sb1, hm_sh, 2048,
                                                nullptr, nullptr, 1 << 30);
  gemm2_k<0><<<dim3(128, 8), 256, 0, stream>>>(hm_sh, 2048, w2t_sh, 2048, 2048,
                                               sb2, sb2 + H, out, nullptr, nullptr,
                                               1 << 30, 0);

  // routed experts: gemm1 over all 12 (rank,expert) regions in one dispatch,
  // then gemm2 as two rank-sliced dispatches (stream-serialized -> atomic-free RMW)
  gemm1_k<1><<<dim3(RTILES, 8), 256, 0, stream>>>(xb, H, w1t + (size_t)2 * H * H, H, H,
                                                  rb1, hm_r, H, asg, g, RCAP);
  gemm2_k<3><<<dim3(134, 8), 256, 0, stream>>>(hm_r, H, w2t_r, H, H,
                                               rb2, nullptr, out, asg, g, RCAP, 0);
  gemm2_k<3><<<dim3(RTILES, 8), 256, 0, stream>>>(hm_r, H, w2t_r, H, H,
                                                  rb2, nullptr, out, asg, g, RCAP, 1);
}

// Round 2
// 837.927 us; speedup vs baseline: 1.0803x; 1.0803x over previous
//
#include <hip/hip_runtime.h>
#include <hip/hip_bf16.h>

#define H 1024
#define B_TOK 16384
#define RTILES 262            // covers worst padded slot total 33408 (261 tiles) + margin
#define RCAP   (RTILES * 128) // asg / routed-hm row capacity (33536)

typedef __attribute__((ext_vector_type(8))) short s16x8;
typedef __attribute__((ext_vector_type(4))) float f32x4;

__device__ __forceinline__ short f2bf(float f) {
  __hip_bfloat16 h = __float2bfloat16(f);
  return __builtin_bit_cast(short, h);
}
__device__ __forceinline__ float bf2f(short s) {
  __hip_bfloat16 h = __builtin_bit_cast(__hip_bfloat16, s);
  return __bfloat162float(h);
}

// fast tanh: 1 - 2/(e^{2x}+1); exact at +-inf tails, ~1e-7 rel err, way below bf16
__device__ __forceinline__ float fast_tanh(float x) {
  const float e = __expf(2.f * x);
  return 1.f - __fdividef(2.f, e + 1.f);
}

__device__ __forceinline__ void load_lds16(const short* g, short* l) {
  __builtin_amdgcn_global_load_lds((const __attribute__((address_space(1))) void*)g,
                                   (__attribute__((address_space(3))) void*)l,
                                   16, 0, 0);
}

// ---------------- convert x -> bf16 ----------------
__global__ void cvt_x_k(const float* __restrict__ x, short* __restrict__ xb) {
  const size_t i = ((size_t)blockIdx.x * blockDim.x + threadIdx.x) * 8;
  const float4 a = *(const float4*)(x + i);
  const float4 b = *(const float4*)(x + i + 4);
  s16x8 v;
  v[0] = f2bf(a.x); v[1] = f2bf(a.y); v[2] = f2bf(a.z); v[3] = f2bf(a.w);
  v[4] = f2bf(b.x); v[5] = f2bf(b.y); v[6] = f2bf(b.z); v[7] = f2bf(b.w);
  *(s16x8*)(xb + i) = v;
}

// ---------------- transpose+convert weights ----------------
// z 0..7: w1 (shared e0,e1 then routed) -> w1t [8][1024][1024]
// z 8..9: shared w2 -> w2t_sh [1024][2048] (K-merged, col offset e*1024)
// z 10..15: routed w2 -> w2t_r [6][1024][1024]
__global__ void transpose_k(const float* __restrict__ sw1, const float* __restrict__ rw1,
                            const float* __restrict__ sw2, const float* __restrict__ rw2,
                            short* __restrict__ w1t, short* __restrict__ w2t_sh,
                            short* __restrict__ w2t_r) {
  __shared__ float tile[64][65];
  const int z = blockIdx.z;
  const float* src;
  short* dst;
  int ldd = H, koff = 0;
  if (z < 8) {
    src = (z < 2) ? sw1 + (size_t)z * H * H : rw1 + (size_t)(z - 2) * H * H;
    dst = w1t + (size_t)z * H * H;
  } else if (z < 10) {
    const int e = z - 8;
    src = sw2 + (size_t)e * H * H;
    dst = w2t_sh; ldd = 2048; koff = e * 1024;
  } else {
    const int e = z - 10;
    src = rw2 + (size_t)e * H * H;
    dst = w2t_r + (size_t)e * H * H;
  }
  const int k0 = blockIdx.y * 64, n0 = blockIdx.x * 64;
  const int t = threadIdx.x;
#pragma unroll
  for (int i = 0; i < 4; ++i) {
    const int kk = (t >> 4) + 16 * i;
    const int nn = (t & 15) * 4;
    const float4 v = *(const float4*)(src + (size_t)(k0 + kk) * H + n0 + nn);
    tile[nn + 0][kk] = v.x; tile[nn + 1][kk] = v.y;
    tile[nn + 2][kk] = v.z; tile[nn + 3][kk] = v.w;
  }
  __syncthreads();
  const int nn = t >> 2;
  const int kk = (t & 3) * 16;
  s16x8 o0, o1;
#pragma unroll
  for (int u = 0; u < 8; ++u) {
    o0[u] = f2bf(tile[nn][kk + u]);
    o1[u] = f2bf(tile[nn][kk + 8 + u]);
  }
  short* drow = dst + (size_t)(n0 + nn) * ldd + koff + k0 + kk;
  *(s16x8*)(drow) = o0;
  *(s16x8*)(drow + 8) = o1;
}

// ---------------- router phase 1: logits -> softmax -> top-2 ----------------
__global__ void logits_k(const float* __restrict__ x, const float* __restrict__ rw,
                         const float* __restrict__ rb, int2* __restrict__ tk) {
  const int lane = threadIdx.x & 63;
  const int b = blockIdx.x * 4 + (threadIdx.x >> 6);
  const float* xr = x + (size_t)b * H;
  float p[6] = {0.f, 0.f, 0.f, 0.f, 0.f, 0.f};
  for (int k = lane; k < H; k += 64) {
    const float xv = xr[k];
    const float* r = rw + k * 6;
#pragma unroll
    for (int e = 0; e < 6; ++e) p[e] += xv * r[e];
  }
#pragma unroll
  for (int e = 0; e < 6; ++e) {
    float v = p[e];
    for (int off = 32; off > 0; off >>= 1) v += __shfl_down(v, off);
    p[e] = v;
  }
  if (lane == 0) {
    float lg[6];
    float mx = -1e30f;
#pragma unroll
    for (int e = 0; e < 6; ++e) { lg[e] = p[e] + rb[e]; mx = fmaxf(mx, lg[e]); }
    float s = 0.f;
#pragma unroll
    for (int e = 0; e < 6; ++e) { lg[e] = __expf(lg[e] - mx); s += lg[e]; }
    const float inv = 1.f / s;
#pragma unroll
    for (int e = 0; e < 6; ++e) lg[e] *= inv;
    int i1 = 0;
#pragma unroll
    for (int e = 1; e < 6; ++e) if (lg[e] > lg[i1]) i1 = e;
    int i2 = (i1 == 0) ? 1 : 0;
#pragma unroll
    for (int e = 0; e < 6; ++e) if (e != i1 && lg[e] > lg[i2]) i2 = e;
    int2 v;
    v.x = i1 | ((int)(unsigned short)f2bf(lg[i1]) << 16);
    v.y = i2 | ((int)(unsigned short)f2bf(lg[i2]) << 16);
    tk[b] = v;
  }
}

// g layout: g[0..5]=cnt, g[8..13]=region starts (128-padded), g[14]=padded total,
// g[16..21]=fill counters
__global__ void hist_k(const int2* __restrict__ tk, int* __restrict__ g) {
  __shared__ int h[6];
  const int t = threadIdx.x;
  if (t < 6) h[t] = 0;
  __syncthreads();
  const int2 v = tk[blockIdx.x * 256 + t];
  atomicAdd(&h[v.x & 0xffff], 1);
  atomicAdd(&h[v.y & 0xffff], 1);
  __syncthreads();
  if (t < 6) atomicAdd(&g[t], h[t]);
}

__global__ void prefix_k(int* __restrict__ g) {
  if (threadIdx.x == 0) {
    int run = 0;
#pragma unroll
    for (int e = 0; e < 6; ++e) {
      g[8 + e] = run; g[16 + e] = run;
      run += (g[e] + 127) & ~127;
    }
    g[14] = run;   // <= 33408 worst case
  }
}

// scatter into compacted slot space; asg pre-memset to 0xFF (sentinel -1)
__global__ void scatter_k(const int2* __restrict__ tk, int* __restrict__ g,
                          int* __restrict__ asg) {
  __shared__ int lcnt[6];
  __shared__ int lbase[6];
  const int t = threadIdx.x;
  if (t < 6) lcnt[t] = 0;
  __syncthreads();
  const int tok = blockIdx.x * 256 + t;
  const int2 v = tk[tok];
  const int e1 = v.x & 0xffff, e2 = v.y & 0xffff;
  const int p1 = atomicAdd(&lcnt[e1], 1);
  const int p2 = atomicAdd(&lcnt[e2], 1);
  __syncthreads();
  if (t < 6) lbase[t] = atomicAdd(&g[16 + t], lcnt[t]);
  __syncthreads();
  asg[lbase[e1] + p1] = tok | (v.x & 0xffff0000);
  asg[lbase[e2] + p2] = tok | (v.y & 0xffff0000);
}

// ---------------- GEMM core, BK=64, double-buffered: C[128x128] = A x Bt^T -----
// smem: 2 buffers x 32 chunks x 512 shorts (64 KB). chunk (2*c2+kh) of a buffer
// holds row-tile c2, k-half kh in exact MFMA fragment order
// (lane l: row c2*16+(l&15), k=kh*32+(l>>4)*8+j).
// Pipeline (T3-minimum): prologue stages buf0; per K-step one __syncthreads()
// (its implicit vmcnt(0)+lgkmcnt(0) drain is the buffer-ready wait), then issue
// next-tile global_load_lds into buf^1, then ds_read+MFMA on buf. Stage latency
// overlaps the current tile's compute; one barrier per K-step instead of two.
__device__ __forceinline__ void gemm_core64(const short* __restrict__ A, int lda,
                                            const short* __restrict__ Bt, int ldb, int K,
                                            short* smem, int m0, int n0,
                                            const int* __restrict__ asg, int acap,
                                            f32x4 acc[4][4]) {
  const int tid = threadIdx.x, lane = tid & 63, w = tid >> 6;
  const int q8 = (lane >> 4) * 8, r16 = lane & 15;
  const int wr = w >> 1, wc = w & 1;

  const short* gp[4];
#pragma unroll
  for (int ii = 0; ii < 4; ++ii) {
    const int c2 = w * 4 + ii;      // row-tile index 0..15 (0..7 A, 8..15 B)
    if (c2 < 8) {
      int slot = m0 + c2 * 16 + r16;
      int gr;
      if (asg) {
        int tv = asg[slot] & 0xffff;
        gr = tv < B_TOK ? tv : B_TOK - 1;   // sentinel/pad -> clamp to any valid row
      } else {
        gr = slot < acap ? slot : acap - 1;
      }
      gp[ii] = A + (size_t)gr * lda + q8;
    } else {
      gp[ii] = Bt + (size_t)(n0 + (c2 - 8) * 16 + r16) * ldb + q8;
    }
  }
  short* lw0 = smem + w * 4096;           // this wave's staging region, buffer 0
  short* lw1 = smem + 16384 + w * 4096;   // buffer 1

  // prologue: stage k=0 into buffer 0
#pragma unroll
  for (int i = 0; i < 8; ++i)
    load_lds16(gp[i >> 1] + (i & 1) * 32, lw0 + i * 512);

  int cur = 0;
  for (int k0 = 0; k0 < K; k0 += 64) {
    // compiler emits s_waitcnt vmcnt(0) lgkmcnt(0) before s_barrier: buf[cur]'s
    // stage is complete and every wave's previous-tile ds_reads have landed.
    __syncthreads();
    const short* lc = cur ? smem + 16384 : smem;
    short* lwn = cur ? lw0 : lw1;
    if (k0 + 64 < K) {
#pragma unroll
      for (int i = 0; i < 8; ++i)
        load_lds16(gp[i >> 1] + (k0 + 64) + (i & 1) * 32, lwn + i * 512);
    }
#pragma unroll
    for (int s = 0; s < 2; ++s) {
      s16x8 af[4], bfv[4];
#pragma unroll
      for (int i = 0; i < 4; ++i)
        af[i] = *(const s16x8*)(lc + ((wr * 4 + i) * 2 + s) * 512 + lane * 8);
#pragma unroll
      for (int j = 0; j < 4; ++j)
        bfv[j] = *(const s16x8*)(lc + (16 + (wc * 4 + j) * 2 + s) * 512 + lane * 8);
#pragma unroll
      for (int i = 0; i < 4; ++i)
#pragma unroll
        for (int j = 0; j < 4; ++j)
          acc[i][j] = __builtin_amdgcn_mfma_f32_16x16x32_bf16(af[i], bfv[j], acc[i][j], 0, 0, 0);
    }
    cur ^= 1;
  }
}

// GEMM1: Out = tanh(A @ W1 + b1) bf16, LDS-staged coalesced store.
// ROUTED=1: batched routed experts (expert from region starts, A-gather via asg)
template <int ROUTED>
__global__ __launch_bounds__(256) void gemm1_k(const short* __restrict__ A, int lda,
                                               const short* __restrict__ W1, int ldb, int K,
                                               const float* __restrict__ b1,
                                               short* __restrict__ Out, int ldo,
                                               const int* __restrict__ asg,
                                               const int* __restrict__ g, int rowcap) {
  const int m0 = blockIdx.x * 128, n0 = blockIdx.y * 128;
  const short* Bt = W1;
  const float* bias = b1;
  if (ROUTED) {
    if (m0 >= g[14]) return;
    int e = 0;
#pragma unroll
    for (int j = 1; j < 6; ++j) if (m0 >= g[8 + j]) e = j;
    Bt = W1 + (size_t)e * H * H;
    bias = b1 + (size_t)e * H;
  }
  __shared__ __align__(16) short smem[32768];
  f32x4 acc[4][4];
#pragma unroll
  for (int i = 0; i < 4; ++i)
#pragma unroll
    for (int j = 0; j < 4; ++j) acc[i][j] = (f32x4){0.f, 0.f, 0.f, 0.f};
  gemm_core64(A, lda, Bt, ldb, K, smem, m0, n0, ROUTED ? asg : nullptr, 1 << 30, acc);

  const int tid = threadIdx.x, lane = tid & 63, w = tid >> 6;
  const int wr = w >> 1, wc = w & 1, q = lane >> 4, c16 = lane & 15;
  __syncthreads();
#pragma unroll
  for (int j = 0; j < 4; ++j) {
    const int colL = wc * 64 + j * 16 + c16;
    const float bv = bias[n0 + colL];
#pragma unroll
    for (int i = 0; i < 4; ++i)
#pragma unroll
      for (int r = 0; r < 4; ++r)
        smem[(wr * 64 + i * 16 + q * 4 + r) * 128 + colL] = f2bf(fast_tanh(acc[i][j][r] + bv));
  }
  __syncthreads();
#pragma unroll
  for (int p = 0; p < 8; ++p) {
    const int rowL = p * 16 + (tid >> 4);
    const int colL = (tid & 15) * 8;
    const int gr = m0 + rowL;
    if (gr < rowcap)
      *(s16x8*)(Out + (size_t)gr * ldo + n0 + colL) = *(const s16x8*)(smem + rowL * 128 + colL);
  }
}

// GEMM2: MODE 0 = merged shared store (LDS-staged fp32), MODE 3 = routed atomic-scatter
template <int MODE>
__global__ __launch_bounds__(256) void gemm2_k(const short* __restrict__ A, int lda,
                                               const short* __restrict__ W2, int ldb, int K,
                                               const float* __restrict__ b2a,
                                               const float* __restrict__ b2b,
                                               float* __restrict__ Out,
                                               const int* __restrict__ asg,
                                               const int* __restrict__ g, int acap) {
  const int m0 = blockIdx.x * 128, n0 = blockIdx.y * 128;
  const short* Bt = W2;
  const float* bias = b2a;
  if (MODE == 3) {
    if (m0 >= g[14]) return;
    int e = 0;
#pragma unroll
    for (int j = 1; j < 6; ++j) if (m0 >= g[8 + j]) e = j;
    Bt = W2 + (size_t)e * H * H;
    bias = b2a + (size_t)e * H;
  }
  __shared__ __align__(16) short smem[32768];
  f32x4 acc[4][4];
#pragma unroll
  for (int i = 0; i < 4; ++i)
#pragma unroll
    for (int j = 0; j < 4; ++j) acc[i][j] = (f32x4){0.f, 0.f, 0.f, 0.f};
  gemm_core64(A, lda, Bt, ldb, K, smem, m0, n0, nullptr, acap, acc);

  const int tid = threadIdx.x, lane = tid & 63, w = tid >> 6;
  const int wr = w >> 1, wc = w & 1, q = lane >> 4, c16 = lane & 15;

  if (MODE == 0) {
    float* cs = (float*)smem;  // [64][128]
    __syncthreads();
#pragma unroll
    for (int half = 0; half < 2; ++half) {
      if (wr == half) {
#pragma unroll
        for (int j = 0; j < 4; ++j) {
          const int colL = wc * 64 + j * 16 + c16;
          const float bv = b2a[n0 + colL] + b2b[n0 + colL];
#pragma unroll
          for (int i = 0; i < 4; ++i)
#pragma unroll
            for (int r = 0; r < 4; ++r)
              cs[(i * 16 + q * 4 + r) * 128 + colL] = acc[i][j][r] + bv;
        }
      }
      __syncthreads();
#pragma unroll
      for (int p = 0; p < 8; ++p) {
        const int rowL = p * 8 + (tid >> 5);
        const int colL = (tid & 31) * 4;
        *(float4*)(Out + (size_t)(m0 + half * 64 + rowL) * H + n0 + colL) =
            *(const float4*)(cs + rowL * 128 + colL);
      }
      __syncthreads();
    }
  } else {
    const int mb = m0 + wr * 64, nb = n0 + wc * 64;
#pragma unroll
    for (int i = 0; i < 4; ++i) {
      int av[4];
#pragma unroll
      for (int r = 0; r < 4; ++r) av[r] = asg[mb + i * 16 + q * 4 + r];
#pragma unroll
      for (int j = 0; j < 4; ++j) {
        const int col = nb + j * 16 + c16;
        const float bv = bias[col];
#pragma unroll
        for (int r = 0; r < 4; ++r) {
          if (av[r] == -1) continue;   // pad slot
          const int tok = av[r] & 0xffff;
          const float wt = bf2f((short)((unsigned)av[r] >> 16));
          atomicAdd(&Out[(size_t)tok * H + col], (acc[i][j][r] + bv) * wt);
        }
      }
    }
  }
}

extern "C" void kernel_launch(void* const* d_in, const int* in_sizes, int n_in,
                              void* d_out, int out_size, void* d_ws, size_t ws_size,
                              hipStream_t stream) {
  const float* x        = (const float*)d_in[0];
  const float* sw1      = (const float*)d_in[1];
  const float* sb1      = (const float*)d_in[2];  // [2][1024] flat
  const float* sw2      = (const float*)d_in[3];
  const float* sb2      = (const float*)d_in[4];
  const float* rw1      = (const float*)d_in[5];
  const float* rb1      = (const float*)d_in[6];
  const float* rw2      = (const float*)d_in[7];
  const float* rb2      = (const float*)d_in[8];
  const float* router_w = (const float*)d_in[9];
  const float* router_b = (const float*)d_in[10];
  float* out = (float*)d_out;

  // ws layout (high-water 128.13 MiB, within proven >=128.38 MiB):
  //   xb      [0,          32 MiB)
  //   w1t     [32 MiB,     48 MiB)   [8][1024][1024]
  //   w2t_r   [48 MiB,     60 MiB)   [6][1024][1024]
  //   w2t_sh  [60 MiB,     64 MiB)   [1024][2048]   (dead after shared gemm2)
  //   hm_sh   [64 MiB,    128 MiB)   [16384][2048] bf16 (shared mids; tk overlay)
  //   hm_r    [60 MiB,   ~125.3 MiB) [RCAP][1024] bf16 -- overlaps w2t_sh+hm_sh,
  //           both dead once routed gemm1 launches (stream-ordered)
  //   g       [128 MiB,   +256 B)
  //   asg     [.., +131 KiB)
  char* ws = (char*)d_ws;
  short* xb     = (short*)(ws);
  short* w1t    = (short*)(ws + (size_t)33554432);
  short* w2t_r  = (short*)(ws + (size_t)50331648);
  short* w2t_sh = (short*)(ws + (size_t)62914560);
  short* hm_sh  = (short*)(ws + (size_t)67108864);
  short* hm_r   = (short*)(ws + (size_t)62914560);  // capacity 34816 rows >= 33408 worst
  int2*  tk     = (int2*)hm_sh;                     // consumed before gemms write hm
  int*   g      = (int*)(ws + (size_t)134217728);
  int*   asg    = (int*)(ws + (size_t)134217984);   // RCAP*4

  hipMemsetAsync(g, 0, 64, stream);
  hipMemsetAsync(asg, 0xFF, RCAP * sizeof(int), stream);

  cvt_x_k<<<8192, 256, 0, stream>>>(x, xb);
  transpose_k<<<dim3(16, 16, 16), 256, 0, stream>>>(sw1, rw1, sw2, rw2, w1t, w2t_sh, w2t_r);
  logits_k<<<4096, 256, 0, stream>>>(x, router_w, router_b, tk);
  hist_k<<<64, 256, 0, stream>>>(tk, g);
  prefix_k<<<1, 64, 0, stream>>>(g);
  scatter_k<<<64, 256, 0, stream>>>(tk, g, asg);

  // shared experts, K-merged: GEMM1 N=2048 -> hm_sh[16384][2048]; GEMM2 K=2048 -> out
  gemm1_k<0><<<dim3(128, 16), 256, 0, stream>>>(xb, H, w1t, H, H, sb1, hm_sh, 2048,
                                                nullptr, nullptr, 1 << 30);
  gemm2_k<0><<<dim3(128, 8), 256, 0, stream>>>(hm_sh, 2048, w2t_sh, 2048, 2048,
                                               sb2, sb2 + H, out, nullptr, nullptr, 1 << 30);

  // routed experts, batched single dispatches over padded compacted slots
  gemm1_k<1><<<dim3(RTILES, 8), 256, 0, stream>>>(xb, H, w1t + (size_t)2 * H * H, H, H,
                                                  rb1, hm_r, H, asg, g, RCAP);
  gemm2_k<3><<<dim3(RTILES, 8), 256, 0, stream>>>(hm_r, H, w2t_r, H, H,
                                                  rb2, nullptr, out, asg, g, RCAP);
}

// Round 3
// 791.344 us; speedup vs baseline: 1.1439x; 1.0589x over previous
//
#include <hip/hip_runtime.h>
#include <hip/hip_bf16.h>

#define H 1024
#define B_TOK 16384
#define RTILES 262            // covers worst padded slot total 33408 (261 tiles) + margin
#define RCAP   (RTILES * 128) // asg / routed-hm row capacity (33536)

typedef __attribute__((ext_vector_type(8))) short s16x8;
typedef __attribute__((ext_vector_type(4))) float f32x4;

__device__ __forceinline__ short f2bf(float f) {
  __hip_bfloat16 h = __float2bfloat16(f);
  return __builtin_bit_cast(short, h);
}
__device__ __forceinline__ float bf2f(short s) {
  __hip_bfloat16 h = __builtin_bit_cast(__hip_bfloat16, s);
  return __bfloat162float(h);
}

// fast tanh: 1 - 2/(e^{2x}+1); exact at +-inf tails, ~1e-7 rel err, way below bf16
__device__ __forceinline__ float fast_tanh(float x) {
  const float e = __expf(2.f * x);
  return 1.f - __fdividef(2.f, e + 1.f);
}

__device__ __forceinline__ void load_lds16(const short* g, short* l) {
  __builtin_amdgcn_global_load_lds((const __attribute__((address_space(1))) void*)g,
                                   (__attribute__((address_space(3))) void*)l,
                                   16, 0, 0);
}

// ---------------- convert x -> bf16 ----------------
__global__ void cvt_x_k(const float* __restrict__ x, short* __restrict__ xb) {
  const size_t i = ((size_t)blockIdx.x * blockDim.x + threadIdx.x) * 8;
  const float4 a = *(const float4*)(x + i);
  const float4 b = *(const float4*)(x + i + 4);
  s16x8 v;
  v[0] = f2bf(a.x); v[1] = f2bf(a.y); v[2] = f2bf(a.z); v[3] = f2bf(a.w);
  v[4] = f2bf(b.x); v[5] = f2bf(b.y); v[6] = f2bf(b.z); v[7] = f2bf(b.w);
  *(s16x8*)(xb + i) = v;
}

// ---------------- transpose+convert weights ----------------
// z 0..7: w1 (shared e0,e1 then routed) -> w1t [8][1024][1024]
// z 8..9: shared w2 -> w2t_sh [1024][2048] (K-merged, col offset e*1024)
// z 10..15: routed w2 -> w2t_r [6][1024][1024]
__global__ void transpose_k(const float* __restrict__ sw1, const float* __restrict__ rw1,
                            const float* __restrict__ sw2, const float* __restrict__ rw2,
                            short* __restrict__ w1t, short* __restrict__ w2t_sh,
                            short* __restrict__ w2t_r) {
  __shared__ float tile[64][65];
  const int z = blockIdx.z;
  const float* src;
  short* dst;
  int ldd = H, koff = 0;
  if (z < 8) {
    src = (z < 2) ? sw1 + (size_t)z * H * H : rw1 + (size_t)(z - 2) * H * H;
    dst = w1t + (size_t)z * H * H;
  } else if (z < 10) {
    const int e = z - 8;
    src = sw2 + (size_t)e * H * H;
    dst = w2t_sh; ldd = 2048; koff = e * 1024;
  } else {
    const int e = z - 10;
    src = rw2 + (size_t)e * H * H;
    dst = w2t_r + (size_t)e * H * H;
  }
  const int k0 = blockIdx.y * 64, n0 = blockIdx.x * 64;
  const int t = threadIdx.x;
#pragma unroll
  for (int i = 0; i < 4; ++i) {
    const int kk = (t >> 4) + 16 * i;
    const int nn = (t & 15) * 4;
    const float4 v = *(const float4*)(src + (size_t)(k0 + kk) * H + n0 + nn);
    tile[nn + 0][kk] = v.x; tile[nn + 1][kk] = v.y;
    tile[nn + 2][kk] = v.z; tile[nn + 3][kk] = v.w;
  }
  __syncthreads();
  const int nn = t >> 2;
  const int kk = (t & 3) * 16;
  s16x8 o0, o1;
#pragma unroll
  for (int u = 0; u < 8; ++u) {
    o0[u] = f2bf(tile[nn][kk + u]);
    o1[u] = f2bf(tile[nn][kk + 8 + u]);
  }
  short* drow = dst + (size_t)(n0 + nn) * ldd + koff + k0 + kk;
  *(s16x8*)(drow) = o0;
  *(s16x8*)(drow + 8) = o1;
}

// ---------------- router phase 1: logits -> softmax -> top-2 ----------------
__global__ void logits_k(const float* __restrict__ x, const float* __restrict__ rw,
                         const float* __restrict__ rb, int2* __restrict__ tk) {
  const int lane = threadIdx.x & 63;
  const int b = blockIdx.x * 4 + (threadIdx.x >> 6);
  const float* xr = x + (size_t)b * H;
  float p[6] = {0.f, 0.f, 0.f, 0.f, 0.f, 0.f};
  for (int k = lane; k < H; k += 64) {
    const float xv = xr[k];
    const float* r = rw + k * 6;
#pragma unroll
    for (int e = 0; e < 6; ++e) p[e] += xv * r[e];
  }
#pragma unroll
  for (int e = 0; e < 6; ++e) {
    float v = p[e];
    for (int off = 32; off > 0; off >>= 1) v += __shfl_down(v, off);
    p[e] = v;
  }
  if (lane == 0) {
    float lg[6];
    float mx = -1e30f;
#pragma unroll
    for (int e = 0; e < 6; ++e) { lg[e] = p[e] + rb[e]; mx = fmaxf(mx, lg[e]); }
    float s = 0.f;
#pragma unroll
    for (int e = 0; e < 6; ++e) { lg[e] = __expf(lg[e] - mx); s += lg[e]; }
    const float inv = 1.f / s;
#pragma unroll
    for (int e = 0; e < 6; ++e) lg[e] *= inv;
    int i1 = 0;
#pragma unroll
    for (int e = 1; e < 6; ++e) if (lg[e] > lg[i1]) i1 = e;
    int i2 = (i1 == 0) ? 1 : 0;
#pragma unroll
    for (int e = 0; e < 6; ++e) if (e != i1 && lg[e] > lg[i2]) i2 = e;
    int2 v;
    v.x = i1 | ((int)(unsigned short)f2bf(lg[i1]) << 16);
    v.y = i2 | ((int)(unsigned short)f2bf(lg[i2]) << 16);
    tk[b] = v;
  }
}

// g layout: g[0..5]=cnt, g[8..13]=region starts (128-padded), g[14]=padded total,
// g[16..21]=fill counters
__global__ void hist_k(const int2* __restrict__ tk, int* __restrict__ g) {
  __shared__ int h[6];
  const int t = threadIdx.x;
  if (t < 6) h[t] = 0;
  __syncthreads();
  const int2 v = tk[blockIdx.x * 256 + t];
  atomicAdd(&h[v.x & 0xffff], 1);
  atomicAdd(&h[v.y & 0xffff], 1);
  __syncthreads();
  if (t < 6) atomicAdd(&g[t], h[t]);
}

__global__ void prefix_k(int* __restrict__ g) {
  if (threadIdx.x == 0) {
    int run = 0;
#pragma unroll
    for (int e = 0; e < 6; ++e) {
      g[8 + e] = run; g[16 + e] = run;
      run += (g[e] + 127) & ~127;
    }
    g[14] = run;   // <= 33408 worst case
  }
}

// scatter into compacted slot space; asg pre-memset to 0xFF (sentinel -1)
__global__ void scatter_k(const int2* __restrict__ tk, int* __restrict__ g,
                          int* __restrict__ asg) {
  __shared__ int lcnt[6];
  __shared__ int lbase[6];
  const int t = threadIdx.x;
  if (t < 6) lcnt[t] = 0;
  __syncthreads();
  const int tok = blockIdx.x * 256 + t;
  const int2 v = tk[tok];
  const int e1 = v.x & 0xffff, e2 = v.y & 0xffff;
  const int p1 = atomicAdd(&lcnt[e1], 1);
  const int p2 = atomicAdd(&lcnt[e2], 1);
  __syncthreads();
  if (t < 6) lbase[t] = atomicAdd(&g[16 + t], lcnt[t]);
  __syncthreads();
  asg[lbase[e1] + p1] = tok | (v.x & 0xffff0000);
  asg[lbase[e2] + p2] = tok | (v.y & 0xffff0000);
}

// ---------------- GEMM core, BK=64, counted-vmcnt 3-deep pipeline ----------------
// C[128x128] = A x Bt^T. smem: 2 buffers x 16384 shorts (64 KB). chunk (2*c2+kh)
// of a buffer holds row-tile c2, k-half kh in exact MFMA fragment order
// (lane l: row c2*16+(l&15), k=kh*32+(l>>4)*8+j) -> ds_read lane*8 is conflict-free.
//
// T4 pipeline (loads in flight ACROSS barriers; vmcnt never drains to 0 in loop):
//   prologue: stage tile0->buf0, tile1->buf1 (16 loads in flight)
//   iter t:   vmcnt(8)            my tile-t loads landed (t+1's 8 stay in flight)
//             s_barrier           tile t visible from all waves
//             ds_read s0; MFMA s0 (overlaps s1 reads below)
//             ds_read s1; lgkmcnt(0)+sched_barrier  (all reads of buf[cur] done)
//             s_barrier           buf[cur] free everywhere
//             stage tile t+2 -> buf[cur]   (issue only; lands 2 iters later)
//             MFMA s1             (overlaps the stage)
// Raw __builtin_amdgcn_s_barrier() is essential: __syncthreads() would emit
// s_waitcnt vmcnt(0) and defeat the pipeline (round-2 post-mortem / m99).
__device__ __forceinline__ void gemm_core64(const short* __restrict__ A, int lda,
                                            const short* __restrict__ Bt, int ldb, int K,
                                            short* smem, int m0, int n0,
                                            const int* __restrict__ asg, int acap,
                                            f32x4 acc[4][4]) {
  const int tid = threadIdx.x, lane = tid & 63, w = tid >> 6;
  const int q8 = (lane >> 4) * 8, r16 = lane & 15;
  const int wr = w >> 1, wc = w & 1;

  const short* gp[4];
#pragma unroll
  for (int ii = 0; ii < 4; ++ii) {
    const int c2 = w * 4 + ii;      // row-tile index 0..15 (0..7 A, 8..15 B)
    if (c2 < 8) {
      int slot = m0 + c2 * 16 + r16;
      int gr;
      if (asg) {
        int tv = asg[slot] & 0xffff;
        gr = tv < B_TOK ? tv : B_TOK - 1;   // sentinel/pad -> clamp to any valid row
      } else {
        gr = slot < acap ? slot : acap - 1;
      }
      gp[ii] = A + (size_t)gr * lda + q8;
    } else {
      gp[ii] = Bt + (size_t)(n0 + (c2 - 8) * 16 + r16) * ldb + q8;
    }
  }
  short* lw0 = smem + w * 4096;           // this wave's staging region, buffer 0
  short* lw1 = smem + 16384 + w * 4096;   // buffer 1

  // prologue: stage tile 0 -> buf0, tile 1 -> buf1 (16 loads outstanding)
#pragma unroll
  for (int i = 0; i < 8; ++i)
    load_lds16(gp[i >> 1] + (i & 1) * 32, lw0 + i * 512);
#pragma unroll
  for (int i = 0; i < 8; ++i)
    load_lds16(gp[i >> 1] + 64 + (i & 1) * 32, lw1 + i * 512);

  const int nsteps = K >> 6;
  int cur = 0;
  for (int t = 0; t < nsteps; ++t) {
    if (t + 1 < nsteps)
      asm volatile("s_waitcnt vmcnt(8)" ::: "memory");
    else
      asm volatile("s_waitcnt vmcnt(0)" ::: "memory");
    __builtin_amdgcn_sched_barrier(0);
    __builtin_amdgcn_s_barrier();          // tile t staged everywhere
    const short* lc = cur ? smem + 16384 : smem;
    short* lwn = cur ? lw1 : lw0;

    // s = 0 half: read fragments, compute (overlaps s=1 reads)
    s16x8 af0[4], bf0[4], af1[4], bf1[4];
#pragma unroll
    for (int i = 0; i < 4; ++i)
      af0[i] = *(const s16x8*)(lc + ((wr * 4 + i) * 2 + 0) * 512 + lane * 8);
#pragma unroll
    for (int j = 0; j < 4; ++j)
      bf0[j] = *(const s16x8*)(lc + (16 + (wc * 4 + j) * 2 + 0) * 512 + lane * 8);
    __builtin_amdgcn_s_setprio(1);
#pragma unroll
    for (int i = 0; i < 4; ++i)
#pragma unroll
      for (int j = 0; j < 4; ++j)
        acc[i][j] = __builtin_amdgcn_mfma_f32_16x16x32_bf16(af0[i], bf0[j], acc[i][j], 0, 0, 0);
    __builtin_amdgcn_s_setprio(0);

    // s = 1 half: read fragments, then certify buf[cur] fully read
#pragma unroll
    for (int i = 0; i < 4; ++i)
      af1[i] = *(const s16x8*)(lc + ((wr * 4 + i) * 2 + 1) * 512 + lane * 8);
#pragma unroll
    for (int j = 0; j < 4; ++j)
      bf1[j] = *(const s16x8*)(lc + (16 + (wc * 4 + j) * 2 + 1) * 512 + lane * 8);
    asm volatile("s_waitcnt lgkmcnt(0)" ::: "memory");
    __builtin_amdgcn_sched_barrier(0);
    __builtin_amdgcn_s_barrier();          // buf[cur] free everywhere

    // stage tile t+2 into buf[cur] (lands 2 iterations from now)
    if (t + 2 < nsteps) {
#pragma unroll
      for (int i = 0; i < 8; ++i)
        load_lds16(gp[i >> 1] + (t + 2) * 64 + (i & 1) * 32, lwn + i * 512);
    }
    __builtin_amdgcn_s_setprio(1);
#pragma unroll
    for (int i = 0; i < 4; ++i)
#pragma unroll
      for (int j = 0; j < 4; ++j)
        acc[i][j] = __builtin_amdgcn_mfma_f32_16x16x32_bf16(af1[i], bf1[j], acc[i][j], 0, 0, 0);
    __builtin_amdgcn_s_setprio(0);
    cur ^= 1;
  }
}

// GEMM1: Out = tanh(A @ W1 + b1) bf16, LDS-staged coalesced store.
// ROUTED=1: batched routed experts (expert from region starts, A-gather via asg)
template <int ROUTED>
__global__ __launch_bounds__(256) void gemm1_k(const short* __restrict__ A, int lda,
                                               const short* __restrict__ W1, int ldb, int K,
                                               const float* __restrict__ b1,
                                               short* __restrict__ Out, int ldo,
                                               const int* __restrict__ asg,
                                               const int* __restrict__ g, int rowcap) {
  const int m0 = blockIdx.x * 128, n0 = blockIdx.y * 128;
  const short* Bt = W1;
  const float* bias = b1;
  if (ROUTED) {
    if (m0 >= g[14]) return;
    int e = 0;
#pragma unroll
    for (int j = 1; j < 6; ++j) if (m0 >= g[8 + j]) e = j;
    Bt = W1 + (size_t)e * H * H;
    bias = b1 + (size_t)e * H;
  }
  __shared__ __align__(16) short smem[32768];
  f32x4 acc[4][4];
#pragma unroll
  for (int i = 0; i < 4; ++i)
#pragma unroll
    for (int j = 0; j < 4; ++j) acc[i][j] = (f32x4){0.f, 0.f, 0.f, 0.f};
  gemm_core64(A, lda, Bt, ldb, K, smem, m0, n0, ROUTED ? asg : nullptr, 1 << 30, acc);

  const int tid = threadIdx.x, lane = tid & 63, w = tid >> 6;
  const int wr = w >> 1, wc = w & 1, q = lane >> 4, c16 = lane & 15;
  __syncthreads();
#pragma unroll
  for (int j = 0; j < 4; ++j) {
    const int colL = wc * 64 + j * 16 + c16;
    const float bv = bias[n0 + colL];
#pragma unroll
    for (int i = 0; i < 4; ++i)
#pragma unroll
      for (int r = 0; r < 4; ++r)
        smem[(wr * 64 + i * 16 + q * 4 + r) * 128 + colL] = f2bf(fast_tanh(acc[i][j][r] + bv));
  }
  __syncthreads();
#pragma unroll
  for (int p = 0; p < 8; ++p) {
    const int rowL = p * 16 + (tid >> 4);
    const int colL = (tid & 15) * 8;
    const int gr = m0 + rowL;
    if (gr < rowcap)
      *(s16x8*)(Out + (size_t)gr * ldo + n0 + colL) = *(const s16x8*)(smem + rowL * 128 + colL);
  }
}

// GEMM2: MODE 0 = merged shared store (LDS-staged fp32), MODE 3 = routed atomic-scatter
template <int MODE>
__global__ __launch_bounds__(256) void gemm2_k(const short* __restrict__ A, int lda,
                                               const short* __restrict__ W2, int ldb, int K,
                                               const float* __restrict__ b2a,
                                               const float* __restrict__ b2b,
                                               float* __restrict__ Out,
                                               const int* __restrict__ asg,
                                               const int* __restrict__ g, int acap) {
  const int m0 = blockIdx.x * 128, n0 = blockIdx.y * 128;
  const short* Bt = W2;
  const float* bias = b2a;
  if (MODE == 3) {
    if (m0 >= g[14]) return;
    int e = 0;
#pragma unroll
    for (int j = 1; j < 6; ++j) if (m0 >= g[8 + j]) e = j;
    Bt = W2 + (size_t)e * H * H;
    bias = b2a + (size_t)e * H;
  }
  __shared__ __align__(16) short smem[32768];
  f32x4 acc[4][4];
#pragma unroll
  for (int i = 0; i < 4; ++i)
#pragma unroll
    for (int j = 0; j < 4; ++j) acc[i][j] = (f32x4){0.f, 0.f, 0.f, 0.f};
  gemm_core64(A, lda, Bt, ldb, K, smem, m0, n0, nullptr, acap, acc);

  const int tid = threadIdx.x, lane = tid & 63, w = tid >> 6;
  const int wr = w >> 1, wc = w & 1, q = lane >> 4, c16 = lane & 15;

  if (MODE == 0) {
    float* cs = (float*)smem;  // [64][128]
    __syncthreads();
#pragma unroll
    for (int half = 0; half < 2; ++half) {
      if (wr == half) {
#pragma unroll
        for (int j = 0; j < 4; ++j) {
          const int colL = wc * 64 + j * 16 + c16;
          const float bv = b2a[n0 + colL] + b2b[n0 + colL];
#pragma unroll
          for (int i = 0; i < 4; ++i)
#pragma unroll
            for (int r = 0; r < 4; ++r)
              cs[(i * 16 + q * 4 + r) * 128 + colL] = acc[i][j][r] + bv;
        }
      }
      __syncthreads();
#pragma unroll
      for (int p = 0; p < 8; ++p) {
        const int rowL = p * 8 + (tid >> 5);
        const int colL = (tid & 31) * 4;
        *(float4*)(Out + (size_t)(m0 + half * 64 + rowL) * H + n0 + colL) =
            *(const float4*)(cs + rowL * 128 + colL);
      }
      __syncthreads();
    }
  } else {
    const int mb = m0 + wr * 64, nb = n0 + wc * 64;
#pragma unroll
    for (int i = 0; i < 4; ++i) {
      int av[4];
#pragma unroll
      for (int r = 0; r < 4; ++r) av[r] = asg[mb + i * 16 + q * 4 + r];
#pragma unroll
      for (int j = 0; j < 4; ++j) {
        const int col = nb + j * 16 + c16;
        const float bv = bias[col];
#pragma unroll
        for (int r = 0; r < 4; ++r) {
          if (av[r] == -1) continue;   // pad slot
          const int tok = av[r] & 0xffff;
          const float wt = bf2f((short)((unsigned)av[r] >> 16));
          atomicAdd(&Out[(size_t)tok * H + col], (acc[i][j][r] + bv) * wt);
        }
      }
    }
  }
}

extern "C" void kernel_launch(void* const* d_in, const int* in_sizes, int n_in,
                              void* d_out, int out_size, void* d_ws, size_t ws_size,
                              hipStream_t stream) {
  const float* x        = (const float*)d_in[0];
  const float* sw1      = (const float*)d_in[1];
  const float* sb1      = (const float*)d_in[2];  // [2][1024] flat
  const float* sw2      = (const float*)d_in[3];
  const float* sb2      = (const float*)d_in[4];
  const float* rw1      = (const float*)d_in[5];
  const float* rb1      = (const float*)d_in[6];
  const float* rw2      = (const float*)d_in[7];
  const float* rb2      = (const float*)d_in[8];
  const float* router_w = (const float*)d_in[9];
  const float* router_b = (const float*)d_in[10];
  float* out = (float*)d_out;

  // ws layout (high-water 128.13 MiB, within proven >=128.38 MiB):
  //   xb      [0,          32 MiB)
  //   w1t     [32 MiB,     48 MiB)   [8][1024][1024]
  //   w2t_r   [48 MiB,     60 MiB)   [6][1024][1024]
  //   w2t_sh  [60 MiB,     64 MiB)   [1024][2048]   (dead after shared gemm2)
  //   hm_sh   [64 MiB,    128 MiB)   [16384][2048] bf16 (shared mids; tk overlay)
  //   hm_r    [60 MiB,   ~125.3 MiB) [RCAP][1024] bf16 -- overlaps w2t_sh+hm_sh,
  //           both dead once routed gemm1 launches (stream-ordered)
  //   g       [128 MiB,   +256 B)
  //   asg     [.., +131 KiB)
  char* ws = (char*)d_ws;
  short* xb     = (short*)(ws);
  short* w1t    = (short*)(ws + (size_t)33554432);
  short* w2t_r  = (short*)(ws + (size_t)50331648);
  short* w2t_sh = (short*)(ws + (size_t)62914560);
  short* hm_sh  = (short*)(ws + (size_t)67108864);
  short* hm_r   = (short*)(ws + (size_t)62914560);  // capacity 34816 rows >= 33408 worst
  int2*  tk     = (int2*)hm_sh;                     // consumed before gemms write hm
  int*   g      = (int*)(ws + (size_t)134217728);
  int*   asg    = (int*)(ws + (size_t)134217984);   // RCAP*4

  hipMemsetAsync(g, 0, 64, stream);
  hipMemsetAsync(asg, 0xFF, RCAP * sizeof(int), stream);

  cvt_x_k<<<8192, 256, 0, stream>>>(x, xb);
  transpose_k<<<dim3(16, 16, 16), 256, 0, stream>>>(sw1, rw1, sw2, rw2, w1t, w2t_sh, w2t_r);
  logits_k<<<4096, 256, 0, stream>>>(x, router_w, router_b, tk);
  hist_k<<<64, 256, 0, stream>>>(tk, g);
  prefix_k<<<1, 64, 0, stream>>>(g);
  scatter_k<<<64, 256, 0, stream>>>(tk, g, asg);

  // shared experts, K-merged: GEMM1 N=2048 -> hm_sh[16384][2048]; GEMM2 K=2048 -> out
  gemm1_k<0><<<dim3(128, 16), 256, 0, stream>>>(xb, H, w1t, H, H, sb1, hm_sh, 2048,
                                                nullptr, nullptr, 1 << 30);
  gemm2_k<0><<<dim3(128, 8), 256, 0, stream>>>(hm_sh, 2048, w2t_sh, 2048, 2048,
                                               sb2, sb2 + H, out, nullptr, nullptr, 1 << 30);

  // routed experts, batched single dispatches over padded compacted slots
  gemm1_k<1><<<dim3(RTILES, 8), 256, 0, stream>>>(xb, H, w1t + (size_t)2 * H * H, H, H,
                                                  rb1, hm_r, H, asg, g, RCAP);
  gemm2_k<3><<<dim3(RTILES, 8), 256, 0, stream>>>(hm_r, H, w2t_r, H, H,
                                                  rb2, nullptr, out, asg, g, RCAP);
}

// Round 4
// 753.366 us; speedup vs baseline: 1.2016x; 1.0504x over previous
//
#include <hip/hip_runtime.h>
#include <hip/hip_bf16.h>

#define H 1024
#define B_TOK 16384
#define RTILES 134            // 256-row tiles; worst padded slot total 34304
#define RCAP   (RTILES * 256) // asg / routed-hm row capacity (34304)

typedef __attribute__((ext_vector_type(8))) short s16x8;
typedef __attribute__((ext_vector_type(4))) float f32x4;

__device__ __forceinline__ short f2bf(float f) {
  __hip_bfloat16 h = __float2bfloat16(f);
  return __builtin_bit_cast(short, h);
}
__device__ __forceinline__ float bf2f(short s) {
  __hip_bfloat16 h = __builtin_bit_cast(__hip_bfloat16, s);
  return __bfloat162float(h);
}

// fast tanh: 1 - 2/(e^{2x}+1); exact at +-inf tails, ~1e-7 rel err, way below bf16
__device__ __forceinline__ float fast_tanh(float x) {
  const float e = __expf(2.f * x);
  return 1.f - __fdividef(2.f, e + 1.f);
}

__device__ __forceinline__ void load_lds16(const short* g, short* l) {
  __builtin_amdgcn_global_load_lds((const __attribute__((address_space(1))) void*)g,
                                   (__attribute__((address_space(3))) void*)l,
                                   16, 0, 0);
}

// ---------------- convert x -> bf16 ----------------
__global__ void cvt_x_k(const float* __restrict__ x, short* __restrict__ xb) {
  const size_t i = ((size_t)blockIdx.x * blockDim.x + threadIdx.x) * 8;
  const float4 a = *(const float4*)(x + i);
  const float4 b = *(const float4*)(x + i + 4);
  s16x8 v;
  v[0] = f2bf(a.x); v[1] = f2bf(a.y); v[2] = f2bf(a.z); v[3] = f2bf(a.w);
  v[4] = f2bf(b.x); v[5] = f2bf(b.y); v[6] = f2bf(b.z); v[7] = f2bf(b.w);
  *(s16x8*)(xb + i) = v;
}

// ---------------- transpose+convert weights ----------------
// z 0..7: w1 (shared e0,e1 then routed) -> w1t [8][1024][1024]
// z 8..9: shared w2 -> w2t_sh [1024][2048] (K-merged, col offset e*1024)
// z 10..15: routed w2 -> w2t_r [6][1024][1024]
__global__ void transpose_k(const float* __restrict__ sw1, const float* __restrict__ rw1,
                            const float* __restrict__ sw2, const float* __restrict__ rw2,
                            short* __restrict__ w1t, short* __restrict__ w2t_sh,
                            short* __restrict__ w2t_r) {
  __shared__ float tile[64][65];
  const int z = blockIdx.z;
  const float* src;
  short* dst;
  int ldd = H, koff = 0;
  if (z < 8) {
    src = (z < 2) ? sw1 + (size_t)z * H * H : rw1 + (size_t)(z - 2) * H * H;
    dst = w1t + (size_t)z * H * H;
  } else if (z < 10) {
    const int e = z - 8;
    src = sw2 + (size_t)e * H * H;
    dst = w2t_sh; ldd = 2048; koff = e * 1024;
  } else {
    const int e = z - 10;
    src = rw2 + (size_t)e * H * H;
    dst = w2t_r + (size_t)e * H * H;
  }
  const int k0 = blockIdx.y * 64, n0 = blockIdx.x * 64;
  const int t = threadIdx.x;
#pragma unroll
  for (int i = 0; i < 4; ++i) {
    const int kk = (t >> 4) + 16 * i;
    const int nn = (t & 15) * 4;
    const float4 v = *(const float4*)(src + (size_t)(k0 + kk) * H + n0 + nn);
    tile[nn + 0][kk] = v.x; tile[nn + 1][kk] = v.y;
    tile[nn + 2][kk] = v.z; tile[nn + 3][kk] = v.w;
  }
  __syncthreads();
  const int nn = t >> 2;
  const int kk = (t & 3) * 16;
  s16x8 o0, o1;
#pragma unroll
  for (int u = 0; u < 8; ++u) {
    o0[u] = f2bf(tile[nn][kk + u]);
    o1[u] = f2bf(tile[nn][kk + 8 + u]);
  }
  short* drow = dst + (size_t)(n0 + nn) * ldd + koff + k0 + kk;
  *(s16x8*)(drow) = o0;
  *(s16x8*)(drow + 8) = o1;
}

// ---------------- router phase 1: logits -> softmax -> top-2 ----------------
__global__ void logits_k(const float* __restrict__ x, const float* __restrict__ rw,
                         const float* __restrict__ rb, int2* __restrict__ tk) {
  const int lane = threadIdx.x & 63;
  const int b = blockIdx.x * 4 + (threadIdx.x >> 6);
  const float* xr = x + (size_t)b * H;
  float p[6] = {0.f, 0.f, 0.f, 0.f, 0.f, 0.f};
  for (int k = lane; k < H; k += 64) {
    const float xv = xr[k];
    const float* r = rw + k * 6;
#pragma unroll
    for (int e = 0; e < 6; ++e) p[e] += xv * r[e];
  }
#pragma unroll
  for (int e = 0; e < 6; ++e) {
    float v = p[e];
    for (int off = 32; off > 0; off >>= 1) v += __shfl_down(v, off);
    p[e] = v;
  }
  if (lane == 0) {
    float lg[6];
    float mx = -1e30f;
#pragma unroll
    for (int e = 0; e < 6; ++e) { lg[e] = p[e] + rb[e]; mx = fmaxf(mx, lg[e]); }
    float s = 0.f;
#pragma unroll
    for (int e = 0; e < 6; ++e) { lg[e] = __expf(lg[e] - mx); s += lg[e]; }
    const float inv = 1.f / s;
#pragma unroll
    for (int e = 0; e < 6; ++e) lg[e] *= inv;
    int i1 = 0;
#pragma unroll
    for (int e = 1; e < 6; ++e) if (lg[e] > lg[i1]) i1 = e;
    int i2 = (i1 == 0) ? 1 : 0;
#pragma unroll
    for (int e = 0; e < 6; ++e) if (e != i1 && lg[e] > lg[i2]) i2 = e;
    int2 v;
    v.x = i1 | ((int)(unsigned short)f2bf(lg[i1]) << 16);
    v.y = i2 | ((int)(unsigned short)f2bf(lg[i2]) << 16);
    tk[b] = v;
  }
}

// g layout: g[0..5]=cnt, g[8..13]=region starts (256-padded), g[14]=padded total,
// g[16..21]=fill counters
__global__ void hist_k(const int2* __restrict__ tk, int* __restrict__ g) {
  __shared__ int h[6];
  const int t = threadIdx.x;
  if (t < 6) h[t] = 0;
  __syncthreads();
  const int2 v = tk[blockIdx.x * 256 + t];
  atomicAdd(&h[v.x & 0xffff], 1);
  atomicAdd(&h[v.y & 0xffff], 1);
  __syncthreads();
  if (t < 6) atomicAdd(&g[t], h[t]);
}

__global__ void prefix_k(int* __restrict__ g) {
  if (threadIdx.x == 0) {
    int run = 0;
#pragma unroll
    for (int e = 0; e < 6; ++e) {
      g[8 + e] = run; g[16 + e] = run;
      run += (g[e] + 255) & ~255;    // 256-row tiles must not straddle experts
    }
    g[14] = run;   // <= 34304 worst case
  }
}

// scatter into compacted slot space; asg pre-memset to 0xFF (sentinel -1)
__global__ void scatter_k(const int2* __restrict__ tk, int* __restrict__ g,
                          int* __restrict__ asg) {
  __shared__ int lcnt[6];
  __shared__ int lbase[6];
  const int t = threadIdx.x;
  if (t < 6) lcnt[t] = 0;
  __syncthreads();
  const int tok = blockIdx.x * 256 + t;
  const int2 v = tk[tok];
  const int e1 = v.x & 0xffff, e2 = v.y & 0xffff;
  const int p1 = atomicAdd(&lcnt[e1], 1);
  const int p2 = atomicAdd(&lcnt[e2], 1);
  __syncthreads();
  if (t < 6) lbase[t] = atomicAdd(&g[16 + t], lcnt[t]);
  __syncthreads();
  asg[lbase[e1] + p1] = tok | (v.x & 0xffff0000);
  asg[lbase[e2] + p2] = tok | (v.y & 0xffff0000);
}

// ---------- GEMM core, 256x256 tile, BK=64, counted-vmcnt 3-deep pipeline ----------
// C[256x256] = A x Bt^T. 512 threads = 8 waves (2M x 4N); wave output 128x64.
// smem: 2 buffers x 32768 shorts (128 KB). Buffer chunk (2*c2+kh), c2 0..15 =
// A row-tiles, 16..31 = B col-tiles; chunk holds 512 shorts in exact MFMA
// fragment order (lane l: row c2*16+(l&15), k=kh*32+(l>>4)*8+j) -> ds_read
// lane*8 is bank-conflict-free. Wave w stages c2 = w*4..w*4+3 (8 loads/K-step).
//
// T4 pipeline (proven round 3): loads stay in flight ACROSS raw s_barriers;
// vmcnt never drains to 0 in the main loop.
//   prologue: stage tile0->buf0, tile1->buf1 (16 loads in flight)
//   iter t:   vmcnt(8); s_barrier          tile t staged everywhere
//             ds_read s0 (12); MFMA s0 (32, overlaps s1 reads)
//             ds_read s1 (12); lgkmcnt(0); s_barrier   buf[cur] fully read
//             stage tile t+2 -> buf[cur] (8 loads, lands 2 iters later)
//             MFMA s1 (32, overlaps the stage)
// Raw __builtin_amdgcn_s_barrier() is essential: __syncthreads() would emit
// s_waitcnt vmcnt(0) and defeat the pipeline (round-2 post-mortem / m99).
__device__ __forceinline__ void gemm_core256(const short* __restrict__ A, int lda,
                                             const short* __restrict__ Bt, int ldb, int K,
                                             short* smem, int m0, int n0,
                                             const int* __restrict__ asg, int acap,
                                             f32x4 acc[8][4]) {
  const int tid = threadIdx.x, lane = tid & 63, w = tid >> 6;
  const int q8 = (lane >> 4) * 8, r16 = lane & 15;
  const int wr = w >> 2, wc = w & 3;

  const short* gp[4];
#pragma unroll
  for (int ii = 0; ii < 4; ++ii) {
    const int c2 = w * 4 + ii;      // row-tile index 0..31 (0..15 A, 16..31 B)
    if (c2 < 16) {
      int slot = m0 + c2 * 16 + r16;
      int gr;
      if (asg) {
        int tv = asg[slot] & 0xffff;
        gr = tv < B_TOK ? tv : B_TOK - 1;   // sentinel/pad -> clamp to any valid row
      } else {
        gr = slot < acap ? slot : acap - 1;
      }
      gp[ii] = A + (size_t)gr * lda + q8;
    } else {
      gp[ii] = Bt + (size_t)(n0 + (c2 - 16) * 16 + r16) * ldb + q8;
    }
  }
  short* lw0 = smem + w * 4096;           // this wave's staging region, buffer 0
  short* lw1 = smem + 32768 + w * 4096;   // buffer 1

  // prologue: stage tile 0 -> buf0, tile 1 -> buf1 (16 loads outstanding)
#pragma unroll
  for (int i = 0; i < 8; ++i)
    load_lds16(gp[i >> 1] + (i & 1) * 32, lw0 + i * 512);
#pragma unroll
  for (int i = 0; i < 8; ++i)
    load_lds16(gp[i >> 1] + 64 + (i & 1) * 32, lw1 + i * 512);

  const int nsteps = K >> 6;
  int cur = 0;
  for (int t = 0; t < nsteps; ++t) {
    if (t + 1 < nsteps)
      asm volatile("s_waitcnt vmcnt(8)" ::: "memory");
    else
      asm volatile("s_waitcnt vmcnt(0)" ::: "memory");
    __builtin_amdgcn_sched_barrier(0);
    __builtin_amdgcn_s_barrier();          // tile t staged everywhere
    const short* lc = cur ? smem + 32768 : smem;
    short* lwn = cur ? lw1 : lw0;

    // s = 0 half: read fragments, compute (overlaps s=1 reads below)
    s16x8 af0[8], bf0[4], af1[8], bf1[4];
#pragma unroll
    for (int i = 0; i < 8; ++i)
      af0[i] = *(const s16x8*)(lc + ((wr * 8 + i) * 2 + 0) * 512 + lane * 8);
#pragma unroll
    for (int j = 0; j < 4; ++j)
      bf0[j] = *(const s16x8*)(lc + ((16 + wc * 4 + j) * 2 + 0) * 512 + lane * 8);
    __builtin_amdgcn_s_setprio(1);
#pragma unroll
    for (int i = 0; i < 8; ++i)
#pragma unroll
      for (int j = 0; j < 4; ++j)
        acc[i][j] = __builtin_amdgcn_mfma_f32_16x16x32_bf16(af0[i], bf0[j], acc[i][j], 0, 0, 0);
    __builtin_amdgcn_s_setprio(0);

    // s = 1 half: read fragments, then certify buf[cur] fully read
#pragma unroll
    for (int i = 0; i < 8; ++i)
      af1[i] = *(const s16x8*)(lc + ((wr * 8 + i) * 2 + 1) * 512 + lane * 8);
#pragma unroll
    for (int j = 0; j < 4; ++j)
      bf1[j] = *(const s16x8*)(lc + ((16 + wc * 4 + j) * 2 + 1) * 512 + lane * 8);
    asm volatile("s_waitcnt lgkmcnt(0)" ::: "memory");
    __builtin_amdgcn_sched_barrier(0);
    __builtin_amdgcn_s_barrier();          // buf[cur] free everywhere

    // stage tile t+2 into buf[cur] (lands 2 iterations from now)
    if (t + 2 < nsteps) {
#pragma unroll
      for (int i = 0; i < 8; ++i)
        load_lds16(gp[i >> 1] + (t + 2) * 64 + (i & 1) * 32, lwn + i * 512);
    }
    __builtin_amdgcn_s_setprio(1);
#pragma unroll
    for (int i = 0; i < 8; ++i)
#pragma unroll
      for (int j = 0; j < 4; ++j)
        acc[i][j] = __builtin_amdgcn_mfma_f32_16x16x32_bf16(af1[i], bf1[j], acc[i][j], 0, 0, 0);
    __builtin_amdgcn_s_setprio(0);
    cur ^= 1;
  }
}

// GEMM1: Out = tanh(A @ W1 + b1) bf16, LDS-staged coalesced store.
// ROUTED=1: batched routed experts (expert from region starts, A-gather via asg)
template <int ROUTED>
__global__ __launch_bounds__(512, 2) void gemm1_k(const short* __restrict__ A, int lda,
                                                  const short* __restrict__ W1, int ldb, int K,
                                                  const float* __restrict__ b1,
                                                  short* __restrict__ Out, int ldo,
                                                  const int* __restrict__ asg,
                                                  const int* __restrict__ g, int rowcap) {
  const int m0 = blockIdx.x * 256, n0 = blockIdx.y * 256;
  const short* Bt = W1;
  const float* bias = b1;
  if (ROUTED) {
    if (m0 >= g[14]) return;
    int e = 0;
#pragma unroll
    for (int j = 1; j < 6; ++j) if (m0 >= g[8 + j]) e = j;
    Bt = W1 + (size_t)e * H * H;
    bias = b1 + (size_t)e * H;
  }
  __shared__ __align__(16) short smem[65536];
  f32x4 acc[8][4];
#pragma unroll
  for (int i = 0; i < 8; ++i)
#pragma unroll
    for (int j = 0; j < 4; ++j) acc[i][j] = (f32x4){0.f, 0.f, 0.f, 0.f};
  gemm_core256(A, lda, Bt, ldb, K, smem, m0, n0, ROUTED ? asg : nullptr, 1 << 30, acc);

  const int tid = threadIdx.x, lane = tid & 63, w = tid >> 6;
  const int wr = w >> 2, wc = w & 3, q = lane >> 4, c16 = lane & 15;
  __syncthreads();
#pragma unroll
  for (int half = 0; half < 2; ++half) {
    if (wr == half) {
#pragma unroll
      for (int j = 0; j < 4; ++j) {
        const int colL = wc * 64 + j * 16 + c16;
        const float bv = bias[n0 + colL];
#pragma unroll
        for (int i = 0; i < 8; ++i)
#pragma unroll
          for (int r = 0; r < 4; ++r)
            smem[(i * 16 + q * 4 + r) * 256 + colL] = f2bf(fast_tanh(acc[i][j][r] + bv));
      }
    }
    __syncthreads();
#pragma unroll
    for (int p = 0; p < 4; ++p) {
      const int rowL = p * 32 + (tid >> 4);
      const int colL = (tid & 15) * 16;
      const int gr = m0 + half * 128 + rowL;
      if (gr < rowcap) {
        *(s16x8*)(Out + (size_t)gr * ldo + n0 + colL) = *(const s16x8*)(smem + rowL * 256 + colL);
        *(s16x8*)(Out + (size_t)gr * ldo + n0 + colL + 8) =
            *(const s16x8*)(smem + rowL * 256 + colL + 8);
      }
    }
    __syncthreads();
  }
}

// GEMM2: MODE 0 = merged shared store (LDS-staged fp32), MODE 3 = routed atomic-scatter
template <int MODE>
__global__ __launch_bounds__(512, 2) void gemm2_k(const short* __restrict__ A, int lda,
                                                  const short* __restrict__ W2, int ldb, int K,
                                                  const float* __restrict__ b2a,
                                                  const float* __restrict__ b2b,
                                                  float* __restrict__ Out,
                                                  const int* __restrict__ asg,
                                                  const int* __restrict__ g, int acap) {
  const int m0 = blockIdx.x * 256, n0 = blockIdx.y * 256;
  const short* Bt = W2;
  const float* bias = b2a;
  if (MODE == 3) {
    if (m0 >= g[14]) return;
    int e = 0;
#pragma unroll
    for (int j = 1; j < 6; ++j) if (m0 >= g[8 + j]) e = j;
    Bt = W2 + (size_t)e * H * H;
    bias = b2a + (size_t)e * H;
  }
  __shared__ __align__(16) short smem[65536];
  f32x4 acc[8][4];
#pragma unroll
  for (int i = 0; i < 8; ++i)
#pragma unroll
    for (int j = 0; j < 4; ++j) acc[i][j] = (f32x4){0.f, 0.f, 0.f, 0.f};
  gemm_core256(A, lda, Bt, ldb, K, smem, m0, n0, nullptr, acap, acc);

  const int tid = threadIdx.x, lane = tid & 63, w = tid >> 6;
  const int wr = w >> 2, wc = w & 3, q = lane >> 4, c16 = lane & 15;

  if (MODE == 0) {
    float* cs = (float*)smem;  // [128][256] fp32 = 128 KB
    __syncthreads();
#pragma unroll
    for (int half = 0; half < 2; ++half) {
      if (wr == half) {
#pragma unroll
        for (int j = 0; j < 4; ++j) {
          const int colL = wc * 64 + j * 16 + c16;
          const float bv = b2a[n0 + colL] + b2b[n0 + colL];
#pragma unroll
          for (int i = 0; i < 8; ++i)
#pragma unroll
            for (int r = 0; r < 4; ++r)
              cs[(i * 16 + q * 4 + r) * 256 + colL] = acc[i][j][r] + bv;
        }
      }
      __syncthreads();
#pragma unroll
      for (int p = 0; p < 16; ++p) {
        const int idx = p * 512 + tid;
        const int rowL = idx >> 6;
        const int colL = (idx & 63) * 4;
        *(float4*)(Out + (size_t)(m0 + half * 128 + rowL) * H + n0 + colL) =
            *(const float4*)(cs + rowL * 256 + colL);
      }
      __syncthreads();
    }
  } else {
    const int mb = m0 + wr * 128, nb = n0 + wc * 64;
#pragma unroll
    for (int i = 0; i < 8; ++i) {
      int av[4];
#pragma unroll
      for (int r = 0; r < 4; ++r) av[r] = asg[mb + i * 16 + q * 4 + r];
#pragma unroll
      for (int j = 0; j < 4; ++j) {
        const int col = nb + j * 16 + c16;
        const float bv = bias[col];
#pragma unroll
        for (int r = 0; r < 4; ++r) {
          if (av[r] == -1) continue;   // pad slot
          const int tok = av[r] & 0xffff;
          const float wt = bf2f((short)((unsigned)av[r] >> 16));
          atomicAdd(&Out[(size_t)tok * H + col], (acc[i][j][r] + bv) * wt);
        }
      }
    }
  }
}

extern "C" void kernel_launch(void* const* d_in, const int* in_sizes, int n_in,
                              void* d_out, int out_size, void* d_ws, size_t ws_size,
                              hipStream_t stream) {
  const float* x        = (const float*)d_in[0];
  const float* sw1      = (const float*)d_in[1];
  const float* sb1      = (const float*)d_in[2];  // [2][1024] flat
  const float* sw2      = (const float*)d_in[3];
  const float* sb2      = (const float*)d_in[4];
  const float* rw1      = (const float*)d_in[5];
  const float* rb1      = (const float*)d_in[6];
  const float* rw2      = (const float*)d_in[7];
  const float* rb2      = (const float*)d_in[8];
  const float* router_w = (const float*)d_in[9];
  const float* router_b = (const float*)d_in[10];
  float* out = (float*)d_out;

  // ws layout (high-water ~128.13 MiB, within proven >=128.38 MiB):
  //   xb      [0,          32 MiB)
  //   w1t     [32 MiB,     48 MiB)   [8][1024][1024]
  //   w2t_r   [48 MiB,     60 MiB)   [6][1024][1024]
  //   w2t_sh  [60 MiB,     64 MiB)   [1024][2048]   (dead after shared gemm2)
  //   hm_sh   [64 MiB,    128 MiB)   [16384][2048] bf16 (shared mids; tk overlay)
  //   hm_r    [60 MiB,   ~127 MiB)   [RCAP][1024] bf16 -- overlaps w2t_sh+hm_sh,
  //           both dead once routed gemm1 launches (stream-ordered);
  //           34304 rows * 2 KB ends at ~127.0 MiB < 128 MiB
  //   g       [128 MiB,   +256 B)
  //   asg     [.., +134 KiB)
  char* ws = (char*)d_ws;
  short* xb     = (short*)(ws);
  short* w1t    = (short*)(ws + (size_t)33554432);
  short* w2t_r  = (short*)(ws + (size_t)50331648);
  short* w2t_sh = (short*)(ws + (size_t)62914560);
  short* hm_sh  = (short*)(ws + (size_t)67108864);
  short* hm_r   = (short*)(ws + (size_t)62914560);  // capacity 34304 rows, fits < 128 MiB
  int2*  tk     = (int2*)hm_sh;                     // consumed before gemms write hm
  int*   g      = (int*)(ws + (size_t)134217728);
  int*   asg    = (int*)(ws + (size_t)134217984);   // RCAP*4 = 137216 B

  hipMemsetAsync(g, 0, 64, stream);
  hipMemsetAsync(asg, 0xFF, RCAP * sizeof(int), stream);

  cvt_x_k<<<8192, 256, 0, stream>>>(x, xb);
  transpose_k<<<dim3(16, 16, 16), 256, 0, stream>>>(sw1, rw1, sw2, rw2, w1t, w2t_sh, w2t_r);
  logits_k<<<4096, 256, 0, stream>>>(x, router_w, router_b, tk);
  hist_k<<<64, 256, 0, stream>>>(tk, g);
  prefix_k<<<1, 64, 0, stream>>>(g);
  scatter_k<<<64, 256, 0, stream>>>(tk, g, asg);

  // shared experts, K-merged: GEMM1 N=2048 -> hm_sh[16384][2048]; GEMM2 K=2048 -> out
  gemm1_k<0><<<dim3(64, 8), 512, 0, stream>>>(xb, H, w1t, H, H, sb1, hm_sh, 2048,
                                              nullptr, nullptr, 1 << 30);
  gemm2_k<0><<<dim3(64, 4), 512, 0, stream>>>(hm_sh, 2048, w2t_sh, 2048, 2048,
                                              sb2, sb2 + H, out, nullptr, nullptr, 1 << 30);

  // routed experts, batched single dispatches over 256-padded compacted slots
  gemm1_k<1><<<dim3(RTILES, 4), 512, 0, stream>>>(xb, H, w1t + (size_t)2 * H * H, H, H,
                                                  rb1, hm_r, H, asg, g, RCAP);
  gemm2_k<3><<<dim3(RTILES, 4), 512, 0, stream>>>(hm_r, H, w2t_r, H, H,
                                                  rb2, nullptr, out, asg, g, RCAP);
}